// Round 4
// baseline (64.090 us; speedup 1.0000x reference)
//
#include <hip/hip_runtime.h>
#include <hip/hip_bf16.h>

typedef float fx4 __attribute__((ext_vector_type(4)));
typedef short i16x8 __attribute__((ext_vector_type(8)));
typedef unsigned short u16;

#define NEG_INF_F (-9.0e15f)

__device__ inline u16 f2bf(float v){
  __hip_bfloat16 h = __float2bfloat16(v);
  return *reinterpret_cast<u16*>(&h);
}

// ---------------------------------------------------------------------------
// Kernel 1: Wh = x @ W (fp32), f1 = Wh@a1, f2 = Wh@a2 (fp32),
// WhT stored bf16 as [bt][o][j]  (MFMA B-operand friendly layout).
// grid (2, 96), 256 threads; thread = one node n.
// ---------------------------------------------------------------------------
__global__ __launch_bounds__(256) void gat_prep(
    const float* __restrict__ input,   // (8,64,12,512)
    const float* __restrict__ W,       // (64,64)
    const float* __restrict__ Avec,    // (128,1)
    u16*   __restrict__ whT,           // (96,64,512) bf16
    float* __restrict__ f1w,           // (96,512)
    float* __restrict__ f2w)           // (96,512)
{
  __shared__ float Wl[64*64];
  __shared__ float Al[128];
  const int tid = threadIdx.x;
  const int bt  = blockIdx.y;
  const int b   = bt / 12, t = bt % 12;
  const int n   = blockIdx.x * 256 + tid;

  {
    const fx4* src = (const fx4*)W;
    fx4* dst = (fx4*)Wl;
    #pragma unroll
    for (int i = 0; i < 4; ++i) dst[tid + 256*i] = src[tid + 256*i];
    if (tid < 32) ((fx4*)Al)[tid] = ((const fx4*)Avec)[tid];
  }
  __syncthreads();

  // x[b, f, t, n], stride between f = 12*512 = 6144
  const float* xp = input + ((size_t)b*64*12 + t) * 512 + n;

  fx4 acc[16];
  #pragma unroll
  for (int i = 0; i < 16; ++i) acc[i] = (fx4){0.f,0.f,0.f,0.f};

  #pragma unroll 8
  for (int f = 0; f < 64; ++f) {
    float xv = xp[(size_t)f * 6144];
    const fx4* wr = (const fx4*)(Wl + f*64);
    #pragma unroll
    for (int o4 = 0; o4 < 16; ++o4) acc[o4] += xv * wr[o4];
  }

  float s1 = 0.f, s2 = 0.f;
  #pragma unroll
  for (int o4 = 0; o4 < 16; ++o4) {
    fx4 v  = acc[o4];
    fx4 w1 = ((const fx4*)Al)[o4];
    fx4 w2 = ((const fx4*)Al)[o4 + 16];
    s1 += v[0]*w1[0] + v[1]*w1[1] + v[2]*w1[2] + v[3]*w1[3];
    s2 += v[0]*w2[0] + v[1]*w2[1] + v[2]*w2[2] + v[3]*w2[3];
  }
  f1w[bt*512 + n] = s1;
  f2w[bt*512 + n] = s2;

  u16* wp = whT + (size_t)bt*64*512 + n;
  #pragma unroll
  for (int o4 = 0; o4 < 16; ++o4) {
    #pragma unroll
    for (int c = 0; c < 4; ++c)
      wp[(size_t)(o4*4 + c) * 512] = f2bf(acc[o4][c]);
  }
}

// ---------------------------------------------------------------------------
// Kernel 2: masked softmax + PV(MFMA) + ELU.
// grid (16, 96), 256 threads (4 waves), 32 rows/block, 8 rows/wave.
//
// Phase A layout: each 16-lane group owns ONE row per pass; lane owns 32
// columns (j = 4*pos + 64k + c). All 16 adj int4 loads issued upfront and
// compressed to 32-bit masks (sustained MLP, minimal VGPR hold). Exact row
// max via monotonicity: max_e = lrelu(f1 + max_unmasked f2), with the
// unmasked-f2 max done in-lane over registers + a 4-step shfl_xor combine.
// Sum reduction hoisted; normalization deferred past the linear MFMA.
// ---------------------------------------------------------------------------
__global__ __launch_bounds__(256, 4) void gat_attn(
    const int*   __restrict__ adj,   // (96,512,512)
    const u16*   __restrict__ whT,   // (96,64,512) bf16
    const float* __restrict__ f1w,
    const float* __restrict__ f2w,
    float*       __restrict__ out)   // (96,512,64)
{
  __shared__ float f2l[512];
  __shared__ float f1l[32];
  __shared__ float sums[32];
  __shared__ u16   attnl[32*512];    // unnormalized p, bf16, XOR-swizzled

  const int tid = threadIdx.x;
  const int l   = tid & 63;
  const int w   = tid >> 6;
  const int pos = l & 15;            // position within 16-lane group
  const int g   = l >> 4;            // group = row within pass
  const int bt  = blockIdx.y;
  const int it  = blockIdx.x;

  ((float2*)f2l)[tid] = ((const float2*)(f2w + bt*512))[tid];
  if (tid < 32) f1l[tid] = f1w[bt*512 + it*32 + tid];
  __syncthreads();

  // lane-resident f2: f2r[k][c] = f2[4*pos + 64k + c]
  fx4 f2r[8];
  #pragma unroll
  for (int k = 0; k < 8; ++k) f2r[k] = ((const fx4*)f2l)[pos + 16*k];

  const int4* adjp = (const int4*)(adj + (size_t)bt*512*512);
  const int lr0 = w*8 + g;           // local row, pass 0
  const int lr1 = lr0 + 4;           // local row, pass 1
  const int4* rp0 = adjp + (size_t)(it*32 + lr0) * 128;
  const int4* rp1 = adjp + (size_t)(it*32 + lr1) * 128;

  // issue all 16 adj loads (coalesced: per instr 4 rows x 256B)
  int4 A0[8], A1[8];
  #pragma unroll
  for (int k = 0; k < 8; ++k) A0[k] = rp0[pos + 16*k];
  #pragma unroll
  for (int k = 0; k < 8; ++k) A1[k] = rp1[pos + 16*k];

  // compress to bit masks (frees the int4 registers)
  unsigned m0 = 0u, m1 = 0u;
  #pragma unroll
  for (int k = 0; k < 8; ++k) {
    if (A0[k].x > 0) m0 |= 1u << (4*k+0);
    if (A0[k].y > 0) m0 |= 1u << (4*k+1);
    if (A0[k].z > 0) m0 |= 1u << (4*k+2);
    if (A0[k].w > 0) m0 |= 1u << (4*k+3);
  }
  #pragma unroll
  for (int k = 0; k < 8; ++k) {
    if (A1[k].x > 0) m1 |= 1u << (4*k+0);
    if (A1[k].y > 0) m1 |= 1u << (4*k+1);
    if (A1[k].z > 0) m1 |= 1u << (4*k+2);
    if (A1[k].w > 0) m1 |= 1u << (4*k+3);
  }

  float ssum0 = 0.f, ssum1 = 0.f;
  #pragma unroll
  for (int p = 0; p < 2; ++p) {
    const unsigned msk = p ? m1 : m0;
    const int lrw = p ? lr1 : lr0;
    const float f1v = f1l[lrw];

    // in-lane masked max of f2, then 4-step group combine
    float mx = NEG_INF_F;
    #pragma unroll
    for (int k = 0; k < 8; ++k) {
      #pragma unroll
      for (int c = 0; c < 4; ++c)
        mx = fmaxf(mx, ((msk >> (4*k+c)) & 1u) ? f2r[k][c] : NEG_INF_F);
    }
    mx = fmaxf(mx, __shfl_xor(mx, 1));
    mx = fmaxf(mx, __shfl_xor(mx, 2));
    mx = fmaxf(mx, __shfl_xor(mx, 4));
    mx = fmaxf(mx, __shfl_xor(mx, 8));
    const float tM = f1v + mx;
    const float M  = fmaxf(tM, 0.2f*tM);   // exact row max of e (monotone lrelu)

    float sum = 0.f;
    char* abase = (char*)attnl + lrw * 1024;
    const unsigned swz = (unsigned)((lrw & 7) << 4);
    #pragma unroll
    for (int k = 0; k < 8; ++k) {
      ushort4 pk;
      float t, lrv, pv;
      t = f1v + f2r[k][0]; lrv = fmaxf(t, 0.2f*t);
      pv = ((msk>>(4*k+0))&1u) ? __expf(lrv - M) : 0.f; sum += pv; pk.x = f2bf(pv);
      t = f1v + f2r[k][1]; lrv = fmaxf(t, 0.2f*t);
      pv = ((msk>>(4*k+1))&1u) ? __expf(lrv - M) : 0.f; sum += pv; pk.y = f2bf(pv);
      t = f1v + f2r[k][2]; lrv = fmaxf(t, 0.2f*t);
      pv = ((msk>>(4*k+2))&1u) ? __expf(lrv - M) : 0.f; sum += pv; pk.z = f2bf(pv);
      t = f1v + f2r[k][3]; lrv = fmaxf(t, 0.2f*t);
      pv = ((msk>>(4*k+3))&1u) ? __expf(lrv - M) : 0.f; sum += pv; pk.w = f2bf(pv);
      *(ushort4*)(abase + (((unsigned)(8*pos + 128*k)) ^ swz)) = pk;
    }
    if (p == 0) ssum0 = sum; else ssum1 = sum;
  }

  // hoisted sum reduces (two chains, ILP-overlapped), pos 0 publishes
  #pragma unroll
  for (int off = 1; off <= 8; off <<= 1) {
    ssum0 += __shfl_xor(ssum0, off);
    ssum1 += __shfl_xor(ssum1, off);
  }
  if (pos == 0) { sums[lr0] = ssum0; sums[lr1] = ssum1; }
  __syncthreads();

  // ---------------- phase B: h = p @ Wh via MFMA; normalize + ELU ---------
  const int q  = g;                  // l>>4
  const int r  = pos;                // l&15
  const int rt = w & 1;              // row-tile (16 rows)
  const int ct = w >> 1;             // col-tiles ct and ct+2
  const unsigned swzB = (unsigned)((r & 7) << 4);
  const char* aBase = (const char*)attnl + (rt*16 + r) * 1024;
  const u16* wb0 = whT + (size_t)bt*64*512 + (size_t)(ct*16 + r)*512;
  const u16* wb1 = wb0 + 32*512;
  fx4 acc0 = {0,0,0,0}, acc1 = {0,0,0,0};

  #pragma unroll
  for (int jt = 0; jt < 512; jt += 32) {
    i16x8 af = *(const i16x8*)(aBase + (((unsigned)(jt*2 + q*16)) ^ swzB));
    i16x8 b0 = *(const i16x8*)(wb0 + jt + 8*q);
    i16x8 b1 = *(const i16x8*)(wb1 + jt + 8*q);
    acc0 = __builtin_amdgcn_mfma_f32_16x16x32_bf16(af, b0, acc0, 0, 0, 0);
    acc1 = __builtin_amdgcn_mfma_f32_16x16x32_bf16(af, b1, acc1, 0, 0, 0);
  }

  // C/D layout: col = l&15, row = q*4 + rr
  float* op = out + ((size_t)bt*512 + it*32 + rt*16) * 64;
  #pragma unroll
  for (int rr = 0; rr < 4; ++rr) {
    const float rs = 1.0f / sums[rt*16 + q*4 + rr];
    float v0 = acc0[rr] * rs; v0 = v0 > 0.f ? v0 : expm1f(v0);
    float v1 = acc1[rr] * rs; v1 = v1 > 0.f ? v1 : expm1f(v1);
    op[(q*4 + rr)*64 + ct*16      + r] = v0;
    op[(q*4 + rr)*64 + ct*16 + 32 + r] = v1;
  }
}

// ---------------------------------------------------------------------------
extern "C" void kernel_launch(void* const* d_in, const int* in_sizes, int n_in,
                              void* d_out, int out_size, void* d_ws, size_t ws_size,
                              hipStream_t stream) {
  const float* input = (const float*)d_in[0];   // (8,64,12,512) f32
  const int*   adj   = (const int*)  d_in[1];   // (8,12,512,512) i32
  const float* W     = (const float*)d_in[2];   // (64,64) f32
  const float* Avec  = (const float*)d_in[3];   // (128,1) f32
  float* out = (float*)d_out;

  // workspace layout: whT bf16 (6,291,456 B) | f1 (196,608 B) | f2 (196,608 B)
  char* ws = (char*)d_ws;
  u16*   whT = (u16*)ws;
  float* f1w = (float*)(ws + 6291456);
  float* f2w = (float*)(ws + 6291456 + 196608);

  gat_prep<<<dim3(2, 96), 256, 0, stream>>>(input, W, Avec, whT, f1w, f2w);
  gat_attn<<<dim3(16, 96), 256, 0, stream>>>(adj, whT, f1w, f2w, out);
}

// Round 5
// 50.621 us; speedup vs baseline: 1.2661x; 1.2661x over previous
//
#include <hip/hip_runtime.h>
#include <hip/hip_bf16.h>

typedef float fx4 __attribute__((ext_vector_type(4)));
typedef short i16x8 __attribute__((ext_vector_type(8)));
typedef unsigned short u16;

#define NEG_INF_F (-9.0e15f)

__device__ inline u16 f2bf(float v){
  __hip_bfloat16 h = __float2bfloat16(v);
  return *reinterpret_cast<u16*>(&h);
}

// ---------------------------------------------------------------------------
// Kernel 1: Wh = x @ W (fp32), f1 = Wh@a1, f2 = Wh@a2 (fp32).
// Wh emitted bf16 in MFMA B-FRAGMENT-LINEAR layout whB[bt][kt][ct][lane][8]
// (repacked via LDS so global stores are fully coalesced): phase B then reads
// one contiguous 1KB burst per wave-load.
// grid (2, 96), 256 threads; thread = one node n.
// ---------------------------------------------------------------------------
__global__ __launch_bounds__(256) void gat_prep(
    const float* __restrict__ input,   // (8,64,12,512)
    const float* __restrict__ W,       // (64,64)
    const float* __restrict__ Avec,    // (128,1)
    u16*   __restrict__ whB,           // (96,16,4,512) bf16 fragment-linear
    float* __restrict__ f1w,           // (96,512)
    float* __restrict__ f2w)           // (96,512)
{
  __shared__ float Wl[64*64];
  __shared__ float Al[128];
  __shared__ u16   Rp[16384];          // 32KB repack buffer
  const int tid = threadIdx.x;
  const int bt  = blockIdx.y;
  const int b   = bt / 12, t = bt % 12;
  const int xb  = blockIdx.x;
  const int n   = xb * 256 + tid;

  {
    const fx4* src = (const fx4*)W;
    fx4* dst = (fx4*)Wl;
    #pragma unroll
    for (int i = 0; i < 4; ++i) dst[tid + 256*i] = src[tid + 256*i];
    if (tid < 32) ((fx4*)Al)[tid] = ((const fx4*)Avec)[tid];
  }
  __syncthreads();

  const float* xp = input + ((size_t)b*64*12 + t) * 512 + n;

  fx4 acc[16];
  #pragma unroll
  for (int i = 0; i < 16; ++i) acc[i] = (fx4){0.f,0.f,0.f,0.f};

  #pragma unroll 8
  for (int f = 0; f < 64; ++f) {
    float xv = xp[(size_t)f * 6144];
    const fx4* wr = (const fx4*)(Wl + f*64);
    #pragma unroll
    for (int o4 = 0; o4 < 16; ++o4) acc[o4] += xv * wr[o4];
  }

  float s1 = 0.f, s2 = 0.f;
  #pragma unroll
  for (int o4 = 0; o4 < 16; ++o4) {
    fx4 v  = acc[o4];
    fx4 w1 = ((const fx4*)Al)[o4];
    fx4 w2 = ((const fx4*)Al)[o4 + 16];
    s1 += v[0]*w1[0] + v[1]*w1[1] + v[2]*w1[2] + v[3]*w1[3];
    s2 += v[0]*w2[0] + v[1]*w2[1] + v[2]*w2[2] + v[3]*w2[3];
  }
  f1w[bt*512 + n] = s1;
  f2w[bt*512 + n] = s2;

  // repack into fragment order: fragment (kt = n>>5, ct = o>>4), lane
  // l = q*16 + r with q=(n>>3)&3, r=o&15, elem e=n&7.
  // Rp[((kt-kt0)*4 + ct)*512 + l*8 + e]
  const int ktl  = (n >> 5) & 7;          // kt - kt0  (kt0 = xb*8)
  const int q    = (n >> 3) & 3;
  const int e    = n & 7;
  const int rowb = ktl*2048 + q*128 + e;
  #pragma unroll
  for (int o4 = 0; o4 < 16; ++o4) {
    #pragma unroll
    for (int c = 0; c < 4; ++c) {
      const int o = o4*4 + c;
      Rp[rowb + (o >> 4)*512 + (o & 15)*8] = f2bf(acc[o4][c]);
    }
  }
  __syncthreads();

  // coalesced store of the contiguous 32KB whB slice for (bt, kt0..kt0+7)
  uint4* dst = (uint4*)(whB + ((size_t)bt*16 + xb*8) * 2048);
  const uint4* src = (const uint4*)Rp;
  #pragma unroll
  for (int i = 0; i < 8; ++i) dst[tid + 256*i] = src[tid + 256*i];
}

// ---------------------------------------------------------------------------
// Kernel 2: masked softmax via rank-2 factorization + PV(MFMA) + ELU.
// grid (32, 96), 256 threads (4 waves), 16 rows/block, 4 rows/wave.
//
// p = exp(lrelu(f1+f2)-M) = (s>0) ? u_i*v_j : uh_i*vh_j   (exact split)
//   v_j  = exp(f2_j - F2max), vh_j = exp(0.2*(f2_j - F2max))  [per block]
//   u_i  = exp(f1+F2max-M),   uh_i = exp(0.2*(f1+F2max)-M)    [per row]
// M = exact row max (monotone lrelu of masked-max f2, butterfly-reduced).
// Guard: gap = F2max - mx > 80 (incl. all-masked rows) -> exact exp path.
// Normalization deferred past the linear MFMA.
// ---------------------------------------------------------------------------
__global__ __launch_bounds__(256, 4) void gat_attn(
    const int*   __restrict__ adj,   // (96,512,512)
    const u16*   __restrict__ whB,   // (96,16,4,512) bf16 fragment-linear
    const float* __restrict__ f1w,
    const float* __restrict__ f2w,
    float*       __restrict__ out)   // (96,512,64)
{
  __shared__ float f2l[512];
  __shared__ float f1l[16];
  __shared__ float wmax[4];
  __shared__ float sums[16];
  __shared__ u16   attnl[16*512];    // unnormalized p, bf16, XOR-swizzled

  const int tid = threadIdx.x;
  const int l   = tid & 63;
  const int w   = tid >> 6;
  const int bt  = blockIdx.y;
  const int it  = blockIdx.x;

  // stage f2 + block-wide max(f2) + f1 slice
  float2 fv = ((const float2*)(f2w + bt*512))[tid];
  ((float2*)f2l)[tid] = fv;
  float m2 = fmaxf(fv.x, fv.y);
  #pragma unroll
  for (int off = 32; off >= 1; off >>= 1) m2 = fmaxf(m2, __shfl_xor(m2, off));
  if (l == 0) wmax[w] = m2;
  if (tid < 16) f1l[tid] = f1w[bt*512 + it*16 + tid];
  __syncthreads();
  const float F2max = fmaxf(fmaxf(wmax[0], wmax[1]), fmaxf(wmax[2], wmax[3]));

  // lane-resident f2 slices and factor tables (8 exps per lane, per block)
  const fx4 f20 = ((const fx4*)f2l)[l];        // j = 4l .. 4l+3
  const fx4 f21 = ((const fx4*)f2l)[64 + l];   // j = 256+4l ..
  fx4 v0, v1, vh0, vh1;
  #pragma unroll
  for (int c = 0; c < 4; ++c) {
    v0[c]  = __expf(f20[c] - F2max);
    v1[c]  = __expf(f21[c] - F2max);
    vh0[c] = __expf(0.2f*(f20[c] - F2max));
    vh1[c] = __expf(0.2f*(f21[c] - F2max));
  }

  // ---------------- phase A ------------------------------------------------
  const int R0     = w * 4;
  const int row_g0 = it*16 + R0;
  const int4* adj4 = (const int4*)(adj + (size_t)bt*512*512);

  int4 pre[2][2];                    // 2-row lookahead
  #pragma unroll
  for (int p = 0; p < 2; ++p) {
    const int4* ar = adj4 + (size_t)(row_g0 + p) * 128;
    pre[p][0] = ar[l];
    pre[p][1] = ar[64 + l];
  }

  float ssum[4];
  #pragma unroll
  for (int r = 0; r < 4; ++r) {
    const int4 c0 = pre[r & 1][0];
    const int4 c1 = pre[r & 1][1];
    if (r + 2 < 4) {
      const int4* ar = adj4 + (size_t)(row_g0 + r + 2) * 128;
      pre[r & 1][0] = ar[l];
      pre[r & 1][1] = ar[64 + l];
    }
    const float f1v = f1l[R0 + r];

    // exact masked row-max of f2: in-lane candidates + 6-step butterfly
    float mx = NEG_INF_F;
    mx = fmaxf(mx, (c0.x > 0) ? f20[0] : NEG_INF_F);
    mx = fmaxf(mx, (c0.y > 0) ? f20[1] : NEG_INF_F);
    mx = fmaxf(mx, (c0.z > 0) ? f20[2] : NEG_INF_F);
    mx = fmaxf(mx, (c0.w > 0) ? f20[3] : NEG_INF_F);
    mx = fmaxf(mx, (c1.x > 0) ? f21[0] : NEG_INF_F);
    mx = fmaxf(mx, (c1.y > 0) ? f21[1] : NEG_INF_F);
    mx = fmaxf(mx, (c1.z > 0) ? f21[2] : NEG_INF_F);
    mx = fmaxf(mx, (c1.w > 0) ? f21[3] : NEG_INF_F);
    #pragma unroll
    for (int off = 32; off >= 1; off >>= 1) mx = fmaxf(mx, __shfl_xor(mx, off));

    const float tM = f1v + mx;
    const float M  = fmaxf(tM, 0.2f*tM);     // exact row max of e
    const float gap = F2max - mx;

    float sum = 0.f;
    ushort4 pk0, pk1;
    if (gap <= 80.f) {
      // fast rank-2 path (no per-entry exp)
      const float u  = __expf(f1v + F2max - M);
      const float uh = __expf(0.2f*(f1v + F2max) - M);
      const float thr = -f1v;                 // s>0  <=>  f2_j > thr
      float pv;
#define GAT_F(pkf, cc, ff, vv, vvh) { \
      const bool cpos = (ff) > thr; \
      float a = cpos ? (vv) : (vvh); \
      float bb = cpos ? u : uh; \
      pv = ((cc) > 0) ? a*bb : 0.f; sum += pv; pkf = f2bf(pv); }
      GAT_F(pk0.x, c0.x, f20[0], v0[0], vh0[0])
      GAT_F(pk0.y, c0.y, f20[1], v0[1], vh0[1])
      GAT_F(pk0.z, c0.z, f20[2], v0[2], vh0[2])
      GAT_F(pk0.w, c0.w, f20[3], v0[3], vh0[3])
      GAT_F(pk1.x, c1.x, f21[0], v1[0], vh1[0])
      GAT_F(pk1.y, c1.y, f21[1], v1[1], vh1[1])
      GAT_F(pk1.z, c1.z, f21[2], v1[2], vh1[2])
      GAT_F(pk1.w, c1.w, f21[3], v1[3], vh1[3])
#undef GAT_F
    } else {
      // exact exp path (rare; also handles all-masked rows -> uniform)
      const float Mf = (mx == NEG_INF_F) ? NEG_INF_F : M;
      float pv;
#define GAT_S(pkf, cc, ff) { float s = f1v + (ff); float lr = fmaxf(s, 0.2f*s); \
      float ee = ((cc) > 0) ? lr : NEG_INF_F; \
      pv = __expf(ee - Mf); sum += pv; pkf = f2bf(pv); }
      GAT_S(pk0.x, c0.x, f20[0]) GAT_S(pk0.y, c0.y, f20[1])
      GAT_S(pk0.z, c0.z, f20[2]) GAT_S(pk0.w, c0.w, f20[3])
      GAT_S(pk1.x, c1.x, f21[0]) GAT_S(pk1.y, c1.y, f21[1])
      GAT_S(pk1.z, c1.z, f21[2]) GAT_S(pk1.w, c1.w, f21[3])
#undef GAT_S
    }
    ssum[r] = sum;

    const int rowR = R0 + r;
    const unsigned swz = (unsigned)((rowR & 7) << 4);
    char* base = (char*)attnl + rowR * 1024;
    *(ushort4*)(base + (((unsigned)(      8*l)) ^ swz)) = pk0;
    *(ushort4*)(base + (((unsigned)(512 + 8*l)) ^ swz)) = pk1;
  }

  // hoisted sum butterflies (4 chains, ILP-overlapped)
  #pragma unroll
  for (int r = 0; r < 4; ++r) {
    #pragma unroll
    for (int off = 32; off >= 1; off >>= 1) ssum[r] += __shfl_xor(ssum[r], off);
  }
  if (l == 0) {
    #pragma unroll
    for (int r = 0; r < 4; ++r) sums[R0 + r] = ssum[r];
  }
  __syncthreads();

  // ---------------- phase B: h = p @ Wh via MFMA; normalize + ELU ---------
  const int r = l & 15, q = l >> 4;
  const int ct = w;                           // col tile for this wave
  const unsigned swzB = (unsigned)((r & 7) << 4);
  const char* aBase = (const char*)attnl + r * 1024;
  const u16*  wp    = whB + (size_t)bt*32768 + ct*512 + l*8;
  fx4 acc = {0,0,0,0};

  #pragma unroll
  for (int kt = 0; kt < 16; ++kt) {
    i16x8 af = *(const i16x8*)(aBase + (((unsigned)(kt*64 + q*16)) ^ swzB));
    i16x8 bf = *(const i16x8*)(wp + kt*2048);   // 1KB contiguous wave burst
    acc = __builtin_amdgcn_mfma_f32_16x16x32_bf16(af, bf, acc, 0, 0, 0);
  }

  // C/D layout: col = l&15, row = q*4 + rr
  float* op = out + ((size_t)bt*512 + it*16) * 64;
  #pragma unroll
  for (int rr = 0; rr < 4; ++rr) {
    const float rs = 1.0f / sums[q*4 + rr];
    float v = acc[rr] * rs;
    v = v > 0.f ? v : expm1f(v);
    op[(q*4 + rr)*64 + ct*16 + r] = v;
  }
}

// ---------------------------------------------------------------------------
extern "C" void kernel_launch(void* const* d_in, const int* in_sizes, int n_in,
                              void* d_out, int out_size, void* d_ws, size_t ws_size,
                              hipStream_t stream) {
  const float* input = (const float*)d_in[0];   // (8,64,12,512) f32
  const int*   adj   = (const int*)  d_in[1];   // (8,12,512,512) i32
  const float* W     = (const float*)d_in[2];   // (64,64) f32
  const float* Avec  = (const float*)d_in[3];   // (128,1) f32
  float* out = (float*)d_out;

  // workspace layout: whB bf16 (6,291,456 B) | f1 (196,608 B) | f2 (196,608 B)
  char* ws = (char*)d_ws;
  u16*   whB = (u16*)ws;
  float* f1w = (float*)(ws + 6291456);
  float* f2w = (float*)(ws + 6291456 + 196608);

  gat_prep<<<dim3(2, 96), 256, 0, stream>>>(input, W, Avec, whB, f1w, f2w);
  gat_attn<<<dim3(32, 96), 256, 0, stream>>>(adj, whB, f1w, f2w, out);
}